// Round 15
// baseline (83.399 us; speedup 1.0000x reference)
//
#include <hip/hip_runtime.h>
#include <stdint.h>

#define NB   8
#define CH   512
#define NPIX 1024
#define DH   64

typedef float  f32x4  __attribute__((ext_vector_type(4)));
typedef float  f32x16 __attribute__((ext_vector_type(16)));
typedef __bf16 bf16x8 __attribute__((ext_vector_type(8)));
typedef unsigned int u32x4 __attribute__((ext_vector_type(4)));

static __device__ __forceinline__ unsigned short f2bf(float f) {
    unsigned int u = __builtin_bit_cast(unsigned int, f);
    u += 0x7FFFu + ((u >> 16) & 1u);   // RNE
    return (unsigned short)(u >> 16);
}

static __device__ __forceinline__ bf16x8 ld_bf8(const unsigned short* p) {
    return *reinterpret_cast<const bf16x8*>(p);
}

static __device__ __forceinline__ unsigned int cvtpk_bf16(float lo, float hi) {
    unsigned int r;
    asm("v_cvt_pk_bf16_f32 %0,%1,%2" : "=v"(r) : "v"(lo), "v"(hi));
    return r;
}

// raw v_exp_f32 (2^x); |S| < 40 so no range fixup needed.
static __device__ __forceinline__ float fexp2(float x) {
    float r;
    asm("v_exp_f32 %0, %1" : "=v"(r) : "v"(x));
    return r;
}

// v_permlane32_swap_b32 a, b:  a' = [a.lo32 | b.lo32], b' = [a.hi32 | b.hi32]
static __device__ __forceinline__ void plswap(unsigned int& a, unsigned int& b) {
    asm("v_permlane32_swap_b32 %0, %1" : "+v"(a), "+v"(b));
}

// async global->LDS, 16B per lane; LDS dest = wave-uniform base + lane*16
static __device__ __forceinline__ void glds16(const unsigned short* g, void* l) {
    __builtin_amdgcn_global_load_lds(
        (const __attribute__((address_space(1))) unsigned int*)g,
        (__attribute__((address_space(3))) unsigned int*)l,
        16, 0, 0);
}

#define WAIT_VMCNT_8() asm volatile("s_waitcnt vmcnt(8)" ::: "memory")
#define WAIT_VMCNT_4() asm volatile("s_waitcnt vmcnt(4)" ::: "memory")
#define WAIT_VMCNT_3() asm volatile("s_waitcnt vmcnt(3)" ::: "memory")
#define WAIT_VMCNT_0() asm volatile("s_waitcnt vmcnt(0)" ::: "memory")
#define WAIT_LGKM_0()  asm volatile("s_waitcnt lgkmcnt(0)" ::: "memory")

// ---------------- fused prep: weights->bf16 + input transpose -------------
__global__ __launch_bounds__(256) void prep_kernel(
        const float* __restrict__ Wq, const float* __restrict__ Wk,
        const float* __restrict__ Wv, const float* __restrict__ Wo,
        unsigned short* __restrict__ Wbf,
        const float* __restrict__ x, const float* __restrict__ ctx,
        unsigned short* __restrict__ XT, unsigned short* __restrict__ CT) {
    __shared__ float tile[32][33];
    const int bid = blockIdx.x;
    if (bid < 1024) {
        int idx4 = (bid * 256 + threadIdx.x) * 4;      // 0..2^20-1 step 4
        int which = idx4 >> 18;
        int off   = idx4 & 0x3FFFF;
        const float* src = which == 0 ? Wq : which == 1 ? Wk : which == 2 ? Wv : Wo;
        float4 v = *(const float4*)(src + off);
        unsigned int lo = ((unsigned)f2bf(v.y) << 16) | f2bf(v.x);
        unsigned int hi = ((unsigned)f2bf(v.w) << 16) | f2bf(v.z);
        *(uint2*)(Wbf + idx4) = make_uint2(lo, hi);
        return;
    }
    const int t0 = bid - 1024;                 // 0..8191
    const int z  = t0 >> 9;                    // 0..15 : tensor(2) x batch(8)
    const int cx = t0 & 15, ny = (t0 >> 4) & 31;
    const float* src = (z < 8) ? x : ctx;
    unsigned short* dst = (z < 8) ? XT : CT;
    const int b  = z & 7;
    const int c0 = cx * 32, n0 = ny * 32;
    const int t  = threadIdx.x;
    const int r  = t >> 3, ch4 = (t & 7) * 4;
    const float* s = src + (size_t)b * CH * NPIX + (size_t)(c0 + r) * NPIX + n0 + ch4;
    float4 v4 = *(const float4*)s;
    tile[r][ch4] = v4.x; tile[r][ch4 + 1] = v4.y;
    tile[r][ch4 + 2] = v4.z; tile[r][ch4 + 3] = v4.w;
    __syncthreads();
    unsigned int lo = ((unsigned)f2bf(tile[ch4 + 1][r]) << 16) | f2bf(tile[ch4][r]);
    unsigned int hw = ((unsigned)f2bf(tile[ch4 + 3][r]) << 16) | f2bf(tile[ch4 + 2][r]);
    *(uint2*)(dst + (size_t)b * NPIX * CH + (size_t)(n0 + r) * CH + c0 + ch4)
        = make_uint2(lo, hw);
}

// ---------------- 128M x 64N x K512 GEMM core (BK=32) ---------------------
// N-split variant for 2x grid parallelism: B-tile 64 rows, 3 loads/wave/kt
// (A: 2 glds16, B: 1), counted vmcnt(3), 3-buffer single-barrier rotation.
// Waves: wm = wv&1 (M half, 64 rows), wn = wv>>1 (N half, 32 cols).
static __device__ __forceinline__ void gemm128x64(
        const unsigned short* __restrict__ Wp,
        const unsigned short* __restrict__ Xp,
        f32x4 acc[4][2]) {
    __shared__ __align__(16) unsigned short lA[3][128][32];
    __shared__ __align__(16) unsigned short lB[3][64][32];
    const int tid  = threadIdx.x;
    const int lane = tid & 63;
    const int wv   = tid >> 6;
    const int wm   = wv & 1, wn = wv >> 1;

    const unsigned short* gA = Wp + (size_t)(wv * 32 + (lane >> 2)) * CH + (lane & 3) * 8;
    const unsigned short* gB = Xp + (size_t)(wv * 16 + (lane >> 2)) * CH + (lane & 3) * 8;

    auto stage = [&](int kt, int buf) {
        const int k0 = kt * 32;
        char* dA = (char*)&lA[buf][0][0] + wv * 2048;
        char* dB = (char*)&lB[buf][0][0] + wv * 1024;
        glds16(gA + k0,           dA);
        glds16(gA + k0 + 16 * CH, dA + 1024);
        glds16(gB + k0,           dB);
    };

    stage(0, 0);
    stage(1, 1);

#pragma unroll 1
    for (int kt = 0; kt < 16; kt++) {
        if (kt < 15) { WAIT_VMCNT_3(); } else { WAIT_VMCNT_0(); }
        __builtin_amdgcn_s_barrier();
        if (kt + 2 < 16) stage(kt + 2, (kt + 2) % 3);
        const int buf = kt % 3;
        bf16x8 af[4], bfrag[2];
#pragma unroll
        for (int i = 0; i < 4; i++)
            af[i] = ld_bf8(&lA[buf][wm * 64 + i * 16 + (lane & 15)][(lane >> 4) * 8]);
#pragma unroll
        for (int j = 0; j < 2; j++)
            bfrag[j] = ld_bf8(&lB[buf][wn * 32 + j * 16 + (lane & 15)][(lane >> 4) * 8]);
#pragma unroll
        for (int i = 0; i < 4; i++)
#pragma unroll
            for (int j = 0; j < 2; j++)
                acc[i][j] = __builtin_amdgcn_mfma_f32_16x16x32_bf16(af[i], bfrag[j], acc[i][j], 0, 0, 0);
    }
}

// ---------------- fused Q/K/V projection --------------------------------
// Grid 1536 (6 blocks/CU), XCD-grouped: b = id&7. 128M x 64N tiles.
// V stored as [bh][kb=n/32][d&31][d>>5][n%32].
__global__ __launch_bounds__(256) void proj_qkv_kernel(
        const unsigned short* __restrict__ XT, const unsigned short* __restrict__ CT,
        const unsigned short* __restrict__ Wbf,
        const float* __restrict__ bq, const float* __restrict__ bk, const float* __restrict__ bv,
        unsigned short* __restrict__ Q, unsigned short* __restrict__ K, unsigned short* __restrict__ V) {
    const int id = blockIdx.x;
    const int b = id & 7, mode = id >> 9, inner = (id >> 3) & 63;
    const int o0 = (inner & 3) * 128, n0 = (inner >> 2) * 64;
    const unsigned short* W = Wbf + (size_t)mode * CH * CH;
    const unsigned short* X = (mode == 0 ? XT : CT) + (size_t)b * NPIX * CH;
    const float* bias = mode == 0 ? bq : mode == 1 ? bk : bv;

    f32x4 acc[4][2];
#pragma unroll
    for (int i = 0; i < 4; i++)
#pragma unroll
        for (int j = 0; j < 2; j++)
#pragma unroll
            for (int r = 0; r < 4; r++) acc[i][j][r] = 0.f;

    gemm128x64(W + (size_t)o0 * CH, X + (size_t)n0 * CH, acc);

    const int lane = threadIdx.x & 63;
    const int wm = (threadIdx.x >> 6) & 1, wn = threadIdx.x >> 7;
    const float qs = 0.125f * 1.44269504088896340736f;   // dim_head^-0.5 * log2(e)
#pragma unroll
    for (int i = 0; i < 4; i++) {
        const int ob = o0 + wm * 64 + i * 16 + (lane >> 4) * 4;
        const int h = ob >> 6, dd = ob & 63;
        float b4[4];
#pragma unroll
        for (int r = 0; r < 4; r++) b4[r] = bias[ob + r];
#pragma unroll
        for (int j = 0; j < 2; j++) {
            const int n = n0 + wn * 32 + j * 16 + (lane & 15);
            float v[4];
#pragma unroll
            for (int r = 0; r < 4; r++) v[r] = acc[i][j][r] + b4[r];
            if (mode == 0) {
#pragma unroll
                for (int r = 0; r < 4; r++) v[r] *= qs;
            }
            if (mode <= 1) {
                unsigned int lo = (unsigned)f2bf(v[0]) | ((unsigned)f2bf(v[1]) << 16);
                unsigned int hi = (unsigned)f2bf(v[2]) | ((unsigned)f2bf(v[3]) << 16);
                unsigned short* dst = (mode == 0 ? Q : K) +
                    (((size_t)(b * 8 + h) * NPIX) + n) * DH + dd;
                *(uint2*)dst = make_uint2(lo, hi);
            } else {
#pragma unroll
                for (int r = 0; r < 4; r++) {
                    int d = dd + r;
                    V[(((size_t)(b * 8 + h) * 32 + (n >> 5)) * 2048)
                      + (size_t)(d & 31) * 64 + (d >> 5) * 32 + (n & 31)] = f2bf(v[r]);
                }
            }
        }
    }
}

// ---------------- flash attention v14 (unchanged from R14) ----------------
__global__ __launch_bounds__(128) void attn_kernel(
        const unsigned short* __restrict__ Qg, const unsigned short* __restrict__ Kg,
        const unsigned short* __restrict__ Vg, unsigned short* __restrict__ AT) {
    __shared__ __align__(16) unsigned short ldsS[2][2][2][2048]; // [wave][buf][K/V][2048]
    __shared__ float lbuf[64];

    const int p  = blockIdx.x;
    const int local = p >> 3;
    const int bh = ((p & 7) << 3) | (local >> 4);
    const int qb = local & 15;
    const int q0 = qb * 64;
    const int tid = threadIdx.x, wave = tid >> 6, lane = tid & 63;
    const int lq = lane & 31, hi = lane >> 5, lql7 = lq & 7;
    const int key0 = wave * 512;

    const unsigned short* Qp = Qg + ((size_t)bh * NPIX + q0 + lq) * DH + hi * 8;
    bf16x8 qa[4], qbf[4];
#pragma unroll
    for (int ds = 0; ds < 4; ds++) {
        qa[ds]  = ld_bf8(Qp + ds * 16);
        qbf[ds] = ld_bf8(Qp + 32 * DH + ds * 16);
    }

    f32x16 oA0, oA1, oB0, oB1, zro;
#pragma unroll
    for (int r = 0; r < 16; r++) {
        oA0[r] = 0.f; oA1[r] = 0.f; oB0[r] = 0.f; oB1[r] = 0.f; zro[r] = 0.f;
    }
    float lA = 0.f, lB = 0.f;

    const int swz = (((lane & 7) ^ ((lane >> 3) & 7)) << 3);
    const unsigned short* gK = Kg + ((size_t)bh * NPIX + key0 + (lane >> 3)) * DH + swz;
    const unsigned short* gV = Vg + (size_t)bh * 65536 + (size_t)(key0 >> 5) * 2048
                                  + (lane >> 3) * 64 + swz;

    auto stage = [&](int t, int buf) {
        const unsigned short* sk = gK + (size_t)t * 32 * DH;
        char* dK = (char*)&ldsS[wave][buf][0][0];
        glds16(sk,           dK);
        glds16(sk +  8 * DH, dK + 1024);
        glds16(sk + 16 * DH, dK + 2048);
        glds16(sk + 24 * DH, dK + 3072);
        const unsigned short* sv = gV + (size_t)t * 2048;
        char* dV = (char*)&ldsS[wave][buf][1][0];
        glds16(sv,        dV);
        glds16(sv +  512, dV + 1024);
        glds16(sv + 1024, dV + 2048);
        glds16(sv + 1536, dV + 3072);
    };

    stage(0, 0);
    stage(1, 1);

    // ---- prologue: QK(0) (tile 0 staged once vmcnt <= 8)
    f32x16 sA, sB;
    {
        WAIT_VMCNT_8();
        const unsigned short* kb = &ldsS[wave][0][0][0] + lq * 64;
        bf16x8 kf0 = ld_bf8(kb + (((0 + hi) ^ lql7) << 3));
        bf16x8 kf1 = ld_bf8(kb + (((2 + hi) ^ lql7) << 3));
        bf16x8 kf2 = ld_bf8(kb + (((4 + hi) ^ lql7) << 3));
        bf16x8 kf3 = ld_bf8(kb + (((6 + hi) ^ lql7) << 3));
        __builtin_amdgcn_s_setprio(1);
        sA = __builtin_amdgcn_mfma_f32_32x32x16_bf16(kf0, qa[0],  zro, 0, 0, 0);
        sA = __builtin_amdgcn_mfma_f32_32x32x16_bf16(kf1, qa[1],  sA, 0, 0, 0);
        sA = __builtin_amdgcn_mfma_f32_32x32x16_bf16(kf2, qa[2],  sA, 0, 0, 0);
        sA = __builtin_amdgcn_mfma_f32_32x32x16_bf16(kf3, qa[3],  sA, 0, 0, 0);
        sB = __builtin_amdgcn_mfma_f32_32x32x16_bf16(kf0, qbf[0], zro, 0, 0, 0);
        sB = __builtin_amdgcn_mfma_f32_32x32x16_bf16(kf1, qbf[1], sB, 0, 0, 0);
        sB = __builtin_amdgcn_mfma_f32_32x32x16_bf16(kf2, qbf[2], sB, 0, 0, 0);
        sB = __builtin_amdgcn_mfma_f32_32x32x16_bf16(kf3, qbf[3], sB, 0, 0, 0);
        __builtin_amdgcn_s_setprio(0);
    }

#pragma unroll 1
    for (int t = 0; t < 16; ++t) {
        const int cur = t & 1;
        // ---- V(t) ds_reads issued first: latency drains under softmax
        const unsigned short* vb = &ldsS[wave][cur][1][0] + lq * 64;
        bf16x8 v00 = ld_bf8(vb + (((0 + hi) ^ lql7) << 3));   // d=lq,    keys 0-15
        bf16x8 v01 = ld_bf8(vb + (((2 + hi) ^ lql7) << 3));   // d=lq,    keys 16-31
        bf16x8 v10 = ld_bf8(vb + (((4 + hi) ^ lql7) << 3));   // d=32+lq, keys 0-15
        bf16x8 v11 = ld_bf8(vb + (((6 + hi) ^ lql7) << 3));   // d=32+lq, keys 16-31

        // ---- softmax(t) on sA/sB (VALU; consumes scores into pa regs)
#pragma unroll
        for (int r = 0; r < 16; r++) { sA[r] = fexp2(sA[r]); sB[r] = fexp2(sB[r]); }
        {
            float a8[8], b8[8], a4[4], b4[4];
#pragma unroll
            for (int i = 0; i < 8; i++) { a8[i] = sA[2*i] + sA[2*i+1]; b8[i] = sB[2*i] + sB[2*i+1]; }
#pragma unroll
            for (int i = 0; i < 4; i++) { a4[i] = a8[2*i] + a8[2*i+1]; b4[i] = b8[2*i] + b8[2*i+1]; }
            lA += (a4[0] + a4[1]) + (a4[2] + a4[3]);
            lB += (b4[0] + b4[1]) + (b4[2] + b4[3]);
        }
        bf16x8 paA[2], paB[2];
#pragma unroll
        for (int ks = 0; ks < 2; ks++) {
            const int bse = ks * 8;
            unsigned int X0 = cvtpk_bf16(sA[bse + 0], sA[bse + 1]);
            unsigned int X1 = cvtpk_bf16(sA[bse + 2], sA[bse + 3]);
            unsigned int X2 = cvtpk_bf16(sA[bse + 4], sA[bse + 5]);
            unsigned int X3 = cvtpk_bf16(sA[bse + 6], sA[bse + 7]);
            plswap(X0, X2); plswap(X1, X3);
            u32x4 wa; wa[0] = X0; wa[1] = X1; wa[2] = X2; wa[3] = X3;
            paA[ks] = __builtin_bit_cast(bf16x8, wa);
            unsigned int Y0 = cvtpk_bf16(sB[bse + 0], sB[bse + 1]);
            unsigned int Y1 = cvtpk_bf16(sB[bse + 2], sB[bse + 3]);
            unsigned int Y2 = cvtpk_bf16(sB[bse + 4], sB[bse + 5]);
            unsigned int Y3 = cvtpk_bf16(sB[bse + 6], sB[bse + 7]);
            plswap(Y0, Y2); plswap(Y1, Y3);
            u32x4 wb; wb[0] = Y0; wb[1] = Y1; wb[2] = Y2; wb[3] = Y3;
            paB[ks] = __builtin_bit_cast(bf16x8, wb);
        }

        // ---- V in regs; safe to overwrite buf[cur] (K(t) reads retired)
        WAIT_LGKM_0();
        __builtin_amdgcn_sched_barrier(0);
        if (t + 2 < 16) stage(t + 2, cur);
        __builtin_amdgcn_sched_barrier(0);

        // ---- QK(t+1): counted wait (t<14: t+2 outstanding -> vmcnt(8)
        // proves t+1 done; t==14: no stage(16), must drain to 0)
        if (t < 15) {
            if (t < 14) { WAIT_VMCNT_8(); } else { WAIT_VMCNT_0(); }
            const unsigned short* kb = &ldsS[wave][cur ^ 1][0][0] + lq * 64;
            bf16x8 kf0 = ld_bf8(kb + (((0 + hi) ^ lql7) << 3));
            bf16x8 kf1 = ld_bf8(kb + (((2 + hi) ^ lql7) << 3));
            bf16x8 kf2 = ld_bf8(kb + (((4 + hi) ^ lql7) << 3));
            bf16x8 kf3 = ld_bf8(kb + (((6 + hi) ^ lql7) << 3));
            __builtin_amdgcn_s_setprio(1);
            sA = __builtin_amdgcn_mfma_f32_32x32x16_bf16(kf0, qa[0],  zro, 0, 0, 0);
            sA = __builtin_amdgcn_mfma_f32_32x32x16_bf16(kf1, qa[1],  sA, 0, 0, 0);
            sA = __builtin_amdgcn_mfma_f32_32x32x16_bf16(kf2, qa[2],  sA, 0, 0, 0);
            sA = __builtin_amdgcn_mfma_f32_32x32x16_bf16(kf3, qa[3],  sA, 0, 0, 0);
            sB = __builtin_amdgcn_mfma_f32_32x32x16_bf16(kf0, qbf[0], zro, 0, 0, 0);
            sB = __builtin_amdgcn_mfma_f32_32x32x16_bf16(kf1, qbf[1], sB, 0, 0, 0);
            sB = __builtin_amdgcn_mfma_f32_32x32x16_bf16(kf2, qbf[2], sB, 0, 0, 0);
            sB = __builtin_amdgcn_mfma_f32_32x32x16_bf16(kf3, qbf[3], sB, 0, 0, 0);
            __builtin_amdgcn_s_setprio(0);
        }

        // ---- PV(t): issue window covers QK(t+1)'s drain
        __builtin_amdgcn_s_setprio(1);
        oA0 = __builtin_amdgcn_mfma_f32_32x32x16_bf16(paA[0], v00, oA0, 0, 0, 0);
        oB0 = __builtin_amdgcn_mfma_f32_32x32x16_bf16(paB[0], v00, oB0, 0, 0, 0);
        oA1 = __builtin_amdgcn_mfma_f32_32x32x16_bf16(paA[0], v10, oA1, 0, 0, 0);
        oB1 = __builtin_amdgcn_mfma_f32_32x32x16_bf16(paB[0], v10, oB1, 0, 0, 0);
        oA0 = __builtin_amdgcn_mfma_f32_32x32x16_bf16(paA[1], v01, oA0, 0, 0, 0);
        oB0 = __builtin_amdgcn_mfma_f32_32x32x16_bf16(paB[1], v01, oB0, 0, 0, 0);
        oA1 = __builtin_amdgcn_mfma_f32_32x32x16_bf16(paA[1], v11, oA1, 0, 0, 0);
        oB1 = __builtin_amdgcn_mfma_f32_32x32x16_bf16(paB[1], v11, oB1, 0, 0, 0);
        __builtin_amdgcn_s_setprio(0);
    }

    // ---- merge (pure add): wave1 posts into its dead staging LDS; one
    // barrier; wave0 adds + writes.
    lA += __shfl_xor(lA, 32);
    lB += __shfl_xor(lB, 32);
    float* obuf = (float*)&ldsS[1][0][0][0];
    if (wave == 1) {
#pragma unroll
        for (int r = 0; r < 16; r++) {
            obuf[(0 * 16 + r) * 64 + lane] = oA0[r];
            obuf[(1 * 16 + r) * 64 + lane] = oA1[r];
            obuf[(2 * 16 + r) * 64 + lane] = oB0[r];
            obuf[(3 * 16 + r) * 64 + lane] = oB1[r];
        }
        if (lane < 32) { lbuf[lq] = lA; lbuf[32 + lq] = lB; }
    }
    __syncthreads();
    if (wave == 0) {
        float invA = 1.0f / (lA + lbuf[lq]);
        float invB = 1.0f / (lB + lbuf[32 + lq]);
        const int b = bh >> 3, h = bh & 7;
#pragma unroll
        for (int r = 0; r < 16; r++) {
            float a0 = oA0[r] + obuf[(0 * 16 + r) * 64 + lane];
            float a1 = oA1[r] + obuf[(1 * 16 + r) * 64 + lane];
            float b0 = oB0[r] + obuf[(2 * 16 + r) * 64 + lane];
            float b1 = oB1[r] + obuf[(3 * 16 + r) * 64 + lane];
            int crow = (r & 3) + 8 * (r >> 2) + 4 * hi;
            float facA = __shfl(invA, crow);
            float facB = __shfl(invB, crow);
            unsigned short* dA = AT + ((size_t)b * NPIX + q0 + crow) * CH + h * 64 + lq;
            dA[0]  = f2bf(a0 * facA);
            dA[32] = f2bf(a1 * facA);
            unsigned short* dB = AT + ((size_t)b * NPIX + q0 + 32 + crow) * CH + h * 64 + lq;
            dB[0]  = f2bf(b0 * facB);
            dB[32] = f2bf(b1 * facB);
        }
    }
}

// ---------------- output projection (fp32 out + bias) ---------------------
// Grid 512 (2 blocks/CU), XCD-grouped: b = id&7. 128M x 64N tiles.
__global__ __launch_bounds__(256) void proj_out_kernel(
        const unsigned short* __restrict__ AT, const unsigned short* __restrict__ Wo,
        const float* __restrict__ bo, float* __restrict__ out) {
    const int id = blockIdx.x;
    const int b = id & 7, inner = id >> 3;
    const int o0 = (inner & 3) * 128, n0 = (inner >> 2) * 64;
    f32x4 acc[4][2];
#pragma unroll
    for (int i = 0; i < 4; i++)
#pragma unroll
        for (int j = 0; j < 2; j++)
#pragma unroll
            for (int r = 0; r < 4; r++) acc[i][j][r] = 0.f;

    gemm128x64(Wo + (size_t)o0 * CH, AT + ((size_t)b * NPIX + n0) * CH, acc);

    const int lane = threadIdx.x & 63;
    const int wm = (threadIdx.x >> 6) & 1, wn = threadIdx.x >> 7;
#pragma unroll
    for (int i = 0; i < 4; i++) {
        const int ob = o0 + wm * 64 + i * 16 + (lane >> 4) * 4;
        float b4[4];
#pragma unroll
        for (int r = 0; r < 4; r++) b4[r] = bo[ob + r];
#pragma unroll
        for (int j = 0; j < 2; j++) {
            const int n = n0 + wn * 32 + j * 16 + (lane & 15);
#pragma unroll
            for (int r = 0; r < 4; r++)
                out[((size_t)b * CH + ob + r) * NPIX + n] = acc[i][j][r] + b4[r];
        }
    }
}

extern "C" void kernel_launch(void* const* d_in, const int* in_sizes, int n_in,
                              void* d_out, int out_size, void* d_ws, size_t ws_size,
                              hipStream_t stream) {
    const float* x   = (const float*)d_in[0];
    const float* ctx = (const float*)d_in[1];
    const float* Wq  = (const float*)d_in[2];
    const float* bq  = (const float*)d_in[3];
    const float* Wk  = (const float*)d_in[4];
    const float* bk  = (const float*)d_in[5];
    const float* Wv  = (const float*)d_in[6];
    const float* bv  = (const float*)d_in[7];
    const float* Wo  = (const float*)d_in[8];
    const float* bo  = (const float*)d_in[9];
    float* out = (float*)d_out;

    char* ws = (char*)d_ws;
    unsigned short* XT  = (unsigned short*)(ws);                 //  8 MB [b][n][c] bf16
    unsigned short* CT  = (unsigned short*)(ws + 8388608);       //  8 MB
    unsigned short* Wbf = (unsigned short*)(ws + 16777216);      //  2 MB Wq|Wk|Wv|Wo
    unsigned short* Q   = (unsigned short*)(ws + 18874368);      //  8 MB [b][h][n][d]
    unsigned short* K   = (unsigned short*)(ws + 27262976);      //  8 MB [b][h][n][d]
    unsigned short* V   = (unsigned short*)(ws + 35651584);      //  8 MB [bh][kb][d&31][d>>5][k32]
    unsigned short* AT  = XT;   // XT dead after proj_qkv; alias for attention output

    prep_kernel<<<9216, 256, 0, stream>>>(Wq, Wk, Wv, Wo, Wbf, x, ctx, XT, CT);
    proj_qkv_kernel<<<1536, 256, 0, stream>>>(XT, CT, Wbf, bq, bk, bv, Q, K, V);
    attn_kernel<<<1024, 128, 0, stream>>>(Q, K, V, AT);
    proj_out_kernel<<<512, 256, 0, stream>>>(AT, Wbf + 3 * 262144, bo, out);
}

// Round 16
// 79.836 us; speedup vs baseline: 1.0446x; 1.0446x over previous
//
#include <hip/hip_runtime.h>
#include <stdint.h>

#define NB   8
#define CH   512
#define NPIX 1024
#define DH   64

typedef float  f32x4  __attribute__((ext_vector_type(4)));
typedef float  f32x16 __attribute__((ext_vector_type(16)));
typedef __bf16 bf16x8 __attribute__((ext_vector_type(8)));
typedef unsigned int u32x4 __attribute__((ext_vector_type(4)));

static __device__ __forceinline__ unsigned short f2bf(float f) {
    unsigned int u = __builtin_bit_cast(unsigned int, f);
    u += 0x7FFFu + ((u >> 16) & 1u);   // RNE
    return (unsigned short)(u >> 16);
}

static __device__ __forceinline__ bf16x8 ld_bf8(const unsigned short* p) {
    return *reinterpret_cast<const bf16x8*>(p);
}

static __device__ __forceinline__ unsigned int cvtpk_bf16(float lo, float hi) {
    unsigned int r;
    asm("v_cvt_pk_bf16_f32 %0,%1,%2" : "=v"(r) : "v"(lo), "v"(hi));
    return r;
}

// raw v_exp_f32 (2^x); |S| < 40 so no range fixup needed.
static __device__ __forceinline__ float fexp2(float x) {
    float r;
    asm("v_exp_f32 %0, %1" : "=v"(r) : "v"(x));
    return r;
}

// v_permlane32_swap_b32 a, b:  a' = [a.lo32 | b.lo32], b' = [a.hi32 | b.hi32]
static __device__ __forceinline__ void plswap(unsigned int& a, unsigned int& b) {
    asm("v_permlane32_swap_b32 %0, %1" : "+v"(a), "+v"(b));
}

// async global->LDS, 16B per lane; LDS dest = wave-uniform base + lane*16
static __device__ __forceinline__ void glds16(const unsigned short* g, void* l) {
    __builtin_amdgcn_global_load_lds(
        (const __attribute__((address_space(1))) unsigned int*)g,
        (__attribute__((address_space(3))) unsigned int*)l,
        16, 0, 0);
}

#define WAIT_VMCNT_8() asm volatile("s_waitcnt vmcnt(8)" ::: "memory")
#define WAIT_VMCNT_4() asm volatile("s_waitcnt vmcnt(4)" ::: "memory")
#define WAIT_VMCNT_3() asm volatile("s_waitcnt vmcnt(3)" ::: "memory")
#define WAIT_VMCNT_0() asm volatile("s_waitcnt vmcnt(0)" ::: "memory")
#define WAIT_LGKM_0()  asm volatile("s_waitcnt lgkmcnt(0)" ::: "memory")

// ---------------- fused prep: weights->bf16 + input transpose -------------
__global__ __launch_bounds__(256) void prep_kernel(
        const float* __restrict__ Wq, const float* __restrict__ Wk,
        const float* __restrict__ Wv, const float* __restrict__ Wo,
        unsigned short* __restrict__ Wbf,
        const float* __restrict__ x, const float* __restrict__ ctx,
        unsigned short* __restrict__ XT, unsigned short* __restrict__ CT) {
    __shared__ float tile[32][33];
    const int bid = blockIdx.x;
    if (bid < 1024) {
        int idx4 = (bid * 256 + threadIdx.x) * 4;      // 0..2^20-1 step 4
        int which = idx4 >> 18;
        int off   = idx4 & 0x3FFFF;
        const float* src = which == 0 ? Wq : which == 1 ? Wk : which == 2 ? Wv : Wo;
        float4 v = *(const float4*)(src + off);
        unsigned int lo = ((unsigned)f2bf(v.y) << 16) | f2bf(v.x);
        unsigned int hi = ((unsigned)f2bf(v.w) << 16) | f2bf(v.z);
        *(uint2*)(Wbf + idx4) = make_uint2(lo, hi);
        return;
    }
    const int t0 = bid - 1024;                 // 0..8191
    const int z  = t0 >> 9;                    // 0..15 : tensor(2) x batch(8)
    const int cx = t0 & 15, ny = (t0 >> 4) & 31;
    const float* src = (z < 8) ? x : ctx;
    unsigned short* dst = (z < 8) ? XT : CT;
    const int b  = z & 7;
    const int c0 = cx * 32, n0 = ny * 32;
    const int t  = threadIdx.x;
    const int r  = t >> 3, ch4 = (t & 7) * 4;
    const float* s = src + (size_t)b * CH * NPIX + (size_t)(c0 + r) * NPIX + n0 + ch4;
    float4 v4 = *(const float4*)s;
    tile[r][ch4] = v4.x; tile[r][ch4 + 1] = v4.y;
    tile[r][ch4 + 2] = v4.z; tile[r][ch4 + 3] = v4.w;
    __syncthreads();
    unsigned int lo = ((unsigned)f2bf(tile[ch4 + 1][r]) << 16) | f2bf(tile[ch4][r]);
    unsigned int hw = ((unsigned)f2bf(tile[ch4 + 3][r]) << 16) | f2bf(tile[ch4 + 2][r]);
    *(uint2*)(dst + (size_t)b * NPIX * CH + (size_t)(n0 + r) * CH + c0 + ch4)
        = make_uint2(lo, hw);
}

// ---------------- 128x128xK512 GEMM core (BK=32) --------------------------
// 3-buffer rotation, ONE barrier per K-step, staging at iteration top.
static __device__ __forceinline__ void gemm128(
        const unsigned short* __restrict__ Wp,
        const unsigned short* __restrict__ Xp,
        f32x4 acc[4][4]) {
    __shared__ __align__(16) unsigned short lA[3][128][32];
    __shared__ __align__(16) unsigned short lB[3][128][32];
    const int tid  = threadIdx.x;
    const int lane = tid & 63;
    const int wv   = tid >> 6;
    const int wm   = wv & 1, wn = tid >> 7;

    const unsigned short* gA = Wp + (size_t)(wv * 32 + (lane >> 2)) * CH + (lane & 3) * 8;
    const unsigned short* gB = Xp + (size_t)(wv * 32 + (lane >> 2)) * CH + (lane & 3) * 8;

    auto stage = [&](int kt, int buf) {
        const int k0 = kt * 32;
        char* dA = (char*)&lA[buf][0][0] + wv * 2048;
        char* dB = (char*)&lB[buf][0][0] + wv * 2048;
        glds16(gA + k0,           dA);
        glds16(gA + k0 + 16 * CH, dA + 1024);
        glds16(gB + k0,           dB);
        glds16(gB + k0 + 16 * CH, dB + 1024);
    };

    stage(0, 0);
    stage(1, 1);

#pragma unroll 1
    for (int kt = 0; kt < 16; kt++) {
        if (kt < 15) { WAIT_VMCNT_4(); } else { WAIT_VMCNT_0(); }
        __builtin_amdgcn_s_barrier();
        if (kt + 2 < 16) stage(kt + 2, (kt + 2) % 3);
        const int buf = kt % 3;
        bf16x8 af[4], bfrag[4];
#pragma unroll
        for (int i = 0; i < 4; i++)
            af[i] = ld_bf8(&lA[buf][wm * 64 + i * 16 + (lane & 15)][(lane >> 4) * 8]);
#pragma unroll
        for (int j = 0; j < 4; j++)
            bfrag[j] = ld_bf8(&lB[buf][wn * 64 + j * 16 + (lane & 15)][(lane >> 4) * 8]);
#pragma unroll
        for (int i = 0; i < 4; i++)
#pragma unroll
            for (int j = 0; j < 4; j++)
                acc[i][j] = __builtin_amdgcn_mfma_f32_16x16x32_bf16(af[i], bfrag[j], acc[i][j], 0, 0, 0);
    }
}

// ---------------- 128M x 64N x K512 GEMM core (BK=32) ---------------------
// N-split variant: used ONLY by proj_out (grid-starved at 128x128).
static __device__ __forceinline__ void gemm128x64(
        const unsigned short* __restrict__ Wp,
        const unsigned short* __restrict__ Xp,
        f32x4 acc[4][2]) {
    __shared__ __align__(16) unsigned short lA[3][128][32];
    __shared__ __align__(16) unsigned short lB[3][64][32];
    const int tid  = threadIdx.x;
    const int lane = tid & 63;
    const int wv   = tid >> 6;
    const int wm   = wv & 1, wn = wv >> 1;

    const unsigned short* gA = Wp + (size_t)(wv * 32 + (lane >> 2)) * CH + (lane & 3) * 8;
    const unsigned short* gB = Xp + (size_t)(wv * 16 + (lane >> 2)) * CH + (lane & 3) * 8;

    auto stage = [&](int kt, int buf) {
        const int k0 = kt * 32;
        char* dA = (char*)&lA[buf][0][0] + wv * 2048;
        char* dB = (char*)&lB[buf][0][0] + wv * 1024;
        glds16(gA + k0,           dA);
        glds16(gA + k0 + 16 * CH, dA + 1024);
        glds16(gB + k0,           dB);
    };

    stage(0, 0);
    stage(1, 1);

#pragma unroll 1
    for (int kt = 0; kt < 16; kt++) {
        if (kt < 15) { WAIT_VMCNT_3(); } else { WAIT_VMCNT_0(); }
        __builtin_amdgcn_s_barrier();
        if (kt + 2 < 16) stage(kt + 2, (kt + 2) % 3);
        const int buf = kt % 3;
        bf16x8 af[4], bfrag[2];
#pragma unroll
        for (int i = 0; i < 4; i++)
            af[i] = ld_bf8(&lA[buf][wm * 64 + i * 16 + (lane & 15)][(lane >> 4) * 8]);
#pragma unroll
        for (int j = 0; j < 2; j++)
            bfrag[j] = ld_bf8(&lB[buf][wn * 32 + j * 16 + (lane & 15)][(lane >> 4) * 8]);
#pragma unroll
        for (int i = 0; i < 4; i++)
#pragma unroll
            for (int j = 0; j < 2; j++)
                acc[i][j] = __builtin_amdgcn_mfma_f32_16x16x32_bf16(af[i], bfrag[j], acc[i][j], 0, 0, 0);
    }
}

// ---------------- fused Q/K/V projection (R14 form: 128x128, grid 768) ----
// 1D grid, XCD-grouped: b = id&7. V stored as [bh][kb=n/32][d&31][d>>5][n%32].
__global__ __launch_bounds__(256) void proj_qkv_kernel(
        const unsigned short* __restrict__ XT, const unsigned short* __restrict__ CT,
        const unsigned short* __restrict__ Wbf,
        const float* __restrict__ bq, const float* __restrict__ bk, const float* __restrict__ bv,
        unsigned short* __restrict__ Q, unsigned short* __restrict__ K, unsigned short* __restrict__ V) {
    const int id = blockIdx.x;
    const int b = id & 7, mode = id >> 8, inner = (id >> 3) & 31;
    const int o0 = (inner & 3) * 128, n0 = (inner >> 2) * 128;
    const unsigned short* W = Wbf + (size_t)mode * CH * CH;
    const unsigned short* X = (mode == 0 ? XT : CT) + (size_t)b * NPIX * CH;
    const float* bias = mode == 0 ? bq : mode == 1 ? bk : bv;

    f32x4 acc[4][4];
#pragma unroll
    for (int i = 0; i < 4; i++)
#pragma unroll
        for (int j = 0; j < 4; j++)
#pragma unroll
            for (int r = 0; r < 4; r++) acc[i][j][r] = 0.f;

    gemm128(W + (size_t)o0 * CH, X + (size_t)n0 * CH, acc);

    const int lane = threadIdx.x & 63;
    const int wm = (threadIdx.x >> 6) & 1, wn = threadIdx.x >> 7;
    const float qs = 0.125f * 1.44269504088896340736f;   // dim_head^-0.5 * log2(e)
#pragma unroll
    for (int i = 0; i < 4; i++) {
        const int ob = o0 + wm * 64 + i * 16 + (lane >> 4) * 4;
        const int h = ob >> 6, dd = ob & 63;
        float b4[4];
#pragma unroll
        for (int r = 0; r < 4; r++) b4[r] = bias[ob + r];
#pragma unroll
        for (int j = 0; j < 4; j++) {
            const int n = n0 + wn * 64 + j * 16 + (lane & 15);
            float v[4];
#pragma unroll
            for (int r = 0; r < 4; r++) v[r] = acc[i][j][r] + b4[r];
            if (mode == 0) {
#pragma unroll
                for (int r = 0; r < 4; r++) v[r] *= qs;
            }
            if (mode <= 1) {
                unsigned int lo = (unsigned)f2bf(v[0]) | ((unsigned)f2bf(v[1]) << 16);
                unsigned int hi = (unsigned)f2bf(v[2]) | ((unsigned)f2bf(v[3]) << 16);
                unsigned short* dst = (mode == 0 ? Q : K) +
                    (((size_t)(b * 8 + h) * NPIX) + n) * DH + dd;
                *(uint2*)dst = make_uint2(lo, hi);
            } else {
#pragma unroll
                for (int r = 0; r < 4; r++) {
                    int d = dd + r;
                    V[(((size_t)(b * 8 + h) * 32 + (n >> 5)) * 2048)
                      + (size_t)(d & 31) * 64 + (d >> 5) * 32 + (n & 31)] = f2bf(v[r]);
                }
            }
        }
    }
}

// ---------------- flash attention v14 (unchanged from R14) ----------------
__global__ __launch_bounds__(128) void attn_kernel(
        const unsigned short* __restrict__ Qg, const unsigned short* __restrict__ Kg,
        const unsigned short* __restrict__ Vg, unsigned short* __restrict__ AT) {
    __shared__ __align__(16) unsigned short ldsS[2][2][2][2048]; // [wave][buf][K/V][2048]
    __shared__ float lbuf[64];

    const int p  = blockIdx.x;
    const int local = p >> 3;
    const int bh = ((p & 7) << 3) | (local >> 4);
    const int qb = local & 15;
    const int q0 = qb * 64;
    const int tid = threadIdx.x, wave = tid >> 6, lane = tid & 63;
    const int lq = lane & 31, hi = lane >> 5, lql7 = lq & 7;
    const int key0 = wave * 512;

    const unsigned short* Qp = Qg + ((size_t)bh * NPIX + q0 + lq) * DH + hi * 8;
    bf16x8 qa[4], qbf[4];
#pragma unroll
    for (int ds = 0; ds < 4; ds++) {
        qa[ds]  = ld_bf8(Qp + ds * 16);
        qbf[ds] = ld_bf8(Qp + 32 * DH + ds * 16);
    }

    f32x16 oA0, oA1, oB0, oB1, zro;
#pragma unroll
    for (int r = 0; r < 16; r++) {
        oA0[r] = 0.f; oA1[r] = 0.f; oB0[r] = 0.f; oB1[r] = 0.f; zro[r] = 0.f;
    }
    float lA = 0.f, lB = 0.f;

    const int swz = (((lane & 7) ^ ((lane >> 3) & 7)) << 3);
    const unsigned short* gK = Kg + ((size_t)bh * NPIX + key0 + (lane >> 3)) * DH + swz;
    const unsigned short* gV = Vg + (size_t)bh * 65536 + (size_t)(key0 >> 5) * 2048
                                  + (lane >> 3) * 64 + swz;

    auto stage = [&](int t, int buf) {
        const unsigned short* sk = gK + (size_t)t * 32 * DH;
        char* dK = (char*)&ldsS[wave][buf][0][0];
        glds16(sk,           dK);
        glds16(sk +  8 * DH, dK + 1024);
        glds16(sk + 16 * DH, dK + 2048);
        glds16(sk + 24 * DH, dK + 3072);
        const unsigned short* sv = gV + (size_t)t * 2048;
        char* dV = (char*)&ldsS[wave][buf][1][0];
        glds16(sv,        dV);
        glds16(sv +  512, dV + 1024);
        glds16(sv + 1024, dV + 2048);
        glds16(sv + 1536, dV + 3072);
    };

    stage(0, 0);
    stage(1, 1);

    // ---- prologue: QK(0) (tile 0 staged once vmcnt <= 8)
    f32x16 sA, sB;
    {
        WAIT_VMCNT_8();
        const unsigned short* kb = &ldsS[wave][0][0][0] + lq * 64;
        bf16x8 kf0 = ld_bf8(kb + (((0 + hi) ^ lql7) << 3));
        bf16x8 kf1 = ld_bf8(kb + (((2 + hi) ^ lql7) << 3));
        bf16x8 kf2 = ld_bf8(kb + (((4 + hi) ^ lql7) << 3));
        bf16x8 kf3 = ld_bf8(kb + (((6 + hi) ^ lql7) << 3));
        __builtin_amdgcn_s_setprio(1);
        sA = __builtin_amdgcn_mfma_f32_32x32x16_bf16(kf0, qa[0],  zro, 0, 0, 0);
        sA = __builtin_amdgcn_mfma_f32_32x32x16_bf16(kf1, qa[1],  sA, 0, 0, 0);
        sA = __builtin_amdgcn_mfma_f32_32x32x16_bf16(kf2, qa[2],  sA, 0, 0, 0);
        sA = __builtin_amdgcn_mfma_f32_32x32x16_bf16(kf3, qa[3],  sA, 0, 0, 0);
        sB = __builtin_amdgcn_mfma_f32_32x32x16_bf16(kf0, qbf[0], zro, 0, 0, 0);
        sB = __builtin_amdgcn_mfma_f32_32x32x16_bf16(kf1, qbf[1], sB, 0, 0, 0);
        sB = __builtin_amdgcn_mfma_f32_32x32x16_bf16(kf2, qbf[2], sB, 0, 0, 0);
        sB = __builtin_amdgcn_mfma_f32_32x32x16_bf16(kf3, qbf[3], sB, 0, 0, 0);
        __builtin_amdgcn_s_setprio(0);
    }

#pragma unroll 1
    for (int t = 0; t < 16; ++t) {
        const int cur = t & 1;
        // ---- V(t) ds_reads issued first: latency drains under softmax
        const unsigned short* vb = &ldsS[wave][cur][1][0] + lq * 64;
        bf16x8 v00 = ld_bf8(vb + (((0 + hi) ^ lql7) << 3));   // d=lq,    keys 0-15
        bf16x8 v01 = ld_bf8(vb + (((2 + hi) ^ lql7) << 3));   // d=lq,    keys 16-31
        bf16x8 v10 = ld_bf8(vb + (((4 + hi) ^ lql7) << 3));   // d=32+lq, keys 0-15
        bf16x8 v11 = ld_bf8(vb + (((6 + hi) ^ lql7) << 3));   // d=32+lq, keys 16-31

        // ---- softmax(t) on sA/sB (VALU; consumes scores into pa regs)
#pragma unroll
        for (int r = 0; r < 16; r++) { sA[r] = fexp2(sA[r]); sB[r] = fexp2(sB[r]); }
        {
            float a8[8], b8[8], a4[4], b4[4];
#pragma unroll
            for (int i = 0; i < 8; i++) { a8[i] = sA[2*i] + sA[2*i+1]; b8[i] = sB[2*i] + sB[2*i+1]; }
#pragma unroll
            for (int i = 0; i < 4; i++) { a4[i] = a8[2*i] + a8[2*i+1]; b4[i] = b8[2*i] + b8[2*i+1]; }
            lA += (a4[0] + a4[1]) + (a4[2] + a4[3]);
            lB += (b4[0] + b4[1]) + (b4[2] + b4[3]);
        }
        bf16x8 paA[2], paB[2];
#pragma unroll
        for (int ks = 0; ks < 2; ks++) {
            const int bse = ks * 8;
            unsigned int X0 = cvtpk_bf16(sA[bse + 0], sA[bse + 1]);
            unsigned int X1 = cvtpk_bf16(sA[bse + 2], sA[bse + 3]);
            unsigned int X2 = cvtpk_bf16(sA[bse + 4], sA[bse + 5]);
            unsigned int X3 = cvtpk_bf16(sA[bse + 6], sA[bse + 7]);
            plswap(X0, X2); plswap(X1, X3);
            u32x4 wa; wa[0] = X0; wa[1] = X1; wa[2] = X2; wa[3] = X3;
            paA[ks] = __builtin_bit_cast(bf16x8, wa);
            unsigned int Y0 = cvtpk_bf16(sB[bse + 0], sB[bse + 1]);
            unsigned int Y1 = cvtpk_bf16(sB[bse + 2], sB[bse + 3]);
            unsigned int Y2 = cvtpk_bf16(sB[bse + 4], sB[bse + 5]);
            unsigned int Y3 = cvtpk_bf16(sB[bse + 6], sB[bse + 7]);
            plswap(Y0, Y2); plswap(Y1, Y3);
            u32x4 wb; wb[0] = Y0; wb[1] = Y1; wb[2] = Y2; wb[3] = Y3;
            paB[ks] = __builtin_bit_cast(bf16x8, wb);
        }

        // ---- V in regs; safe to overwrite buf[cur] (K(t) reads retired)
        WAIT_LGKM_0();
        __builtin_amdgcn_sched_barrier(0);
        if (t + 2 < 16) stage(t + 2, cur);
        __builtin_amdgcn_sched_barrier(0);

        // ---- QK(t+1): counted wait (t<14: t+2 outstanding -> vmcnt(8)
        // proves t+1 done; t==14: no stage(16), must drain to 0)
        if (t < 15) {
            if (t < 14) { WAIT_VMCNT_8(); } else { WAIT_VMCNT_0(); }
            const unsigned short* kb = &ldsS[wave][cur ^ 1][0][0] + lq * 64;
            bf16x8 kf0 = ld_bf8(kb + (((0 + hi) ^ lql7) << 3));
            bf16x8 kf1 = ld_bf8(kb + (((2 + hi) ^ lql7) << 3));
            bf16x8 kf2 = ld_bf8(kb + (((4 + hi) ^ lql7) << 3));
            bf16x8 kf3 = ld_bf8(kb + (((6 + hi) ^ lql7) << 3));
            __builtin_amdgcn_s_setprio(1);
            sA = __builtin_amdgcn_mfma_f32_32x32x16_bf16(kf0, qa[0],  zro, 0, 0, 0);
            sA = __builtin_amdgcn_mfma_f32_32x32x16_bf16(kf1, qa[1],  sA, 0, 0, 0);
            sA = __builtin_amdgcn_mfma_f32_32x32x16_bf16(kf2, qa[2],  sA, 0, 0, 0);
            sA = __builtin_amdgcn_mfma_f32_32x32x16_bf16(kf3, qa[3],  sA, 0, 0, 0);
            sB = __builtin_amdgcn_mfma_f32_32x32x16_bf16(kf0, qbf[0], zro, 0, 0, 0);
            sB = __builtin_amdgcn_mfma_f32_32x32x16_bf16(kf1, qbf[1], sB, 0, 0, 0);
            sB = __builtin_amdgcn_mfma_f32_32x32x16_bf16(kf2, qbf[2], sB, 0, 0, 0);
            sB = __builtin_amdgcn_mfma_f32_32x32x16_bf16(kf3, qbf[3], sB, 0, 0, 0);
            __builtin_amdgcn_s_setprio(0);
        }

        // ---- PV(t): issue window covers QK(t+1)'s drain
        __builtin_amdgcn_s_setprio(1);
        oA0 = __builtin_amdgcn_mfma_f32_32x32x16_bf16(paA[0], v00, oA0, 0, 0, 0);
        oB0 = __builtin_amdgcn_mfma_f32_32x32x16_bf16(paB[0], v00, oB0, 0, 0, 0);
        oA1 = __builtin_amdgcn_mfma_f32_32x32x16_bf16(paA[0], v10, oA1, 0, 0, 0);
        oB1 = __builtin_amdgcn_mfma_f32_32x32x16_bf16(paB[0], v10, oB1, 0, 0, 0);
        oA0 = __builtin_amdgcn_mfma_f32_32x32x16_bf16(paA[1], v01, oA0, 0, 0, 0);
        oB0 = __builtin_amdgcn_mfma_f32_32x32x16_bf16(paB[1], v01, oB0, 0, 0, 0);
        oA1 = __builtin_amdgcn_mfma_f32_32x32x16_bf16(paA[1], v11, oA1, 0, 0, 0);
        oB1 = __builtin_amdgcn_mfma_f32_32x32x16_bf16(paB[1], v11, oB1, 0, 0, 0);
        __builtin_amdgcn_s_setprio(0);
    }

    // ---- merge (pure add): wave1 posts into its dead staging LDS; one
    // barrier; wave0 adds + writes.
    lA += __shfl_xor(lA, 32);
    lB += __shfl_xor(lB, 32);
    float* obuf = (float*)&ldsS[1][0][0][0];
    if (wave == 1) {
#pragma unroll
        for (int r = 0; r < 16; r++) {
            obuf[(0 * 16 + r) * 64 + lane] = oA0[r];
            obuf[(1 * 16 + r) * 64 + lane] = oA1[r];
            obuf[(2 * 16 + r) * 64 + lane] = oB0[r];
            obuf[(3 * 16 + r) * 64 + lane] = oB1[r];
        }
        if (lane < 32) { lbuf[lq] = lA; lbuf[32 + lq] = lB; }
    }
    __syncthreads();
    if (wave == 0) {
        float invA = 1.0f / (lA + lbuf[lq]);
        float invB = 1.0f / (lB + lbuf[32 + lq]);
        const int b = bh >> 3, h = bh & 7;
#pragma unroll
        for (int r = 0; r < 16; r++) {
            float a0 = oA0[r] + obuf[(0 * 16 + r) * 64 + lane];
            float a1 = oA1[r] + obuf[(1 * 16 + r) * 64 + lane];
            float b0 = oB0[r] + obuf[(2 * 16 + r) * 64 + lane];
            float b1 = oB1[r] + obuf[(3 * 16 + r) * 64 + lane];
            int crow = (r & 3) + 8 * (r >> 2) + 4 * hi;
            float facA = __shfl(invA, crow);
            float facB = __shfl(invB, crow);
            unsigned short* dA = AT + ((size_t)b * NPIX + q0 + crow) * CH + h * 64 + lq;
            dA[0]  = f2bf(a0 * facA);
            dA[32] = f2bf(a1 * facA);
            unsigned short* dB = AT + ((size_t)b * NPIX + q0 + 32 + crow) * CH + h * 64 + lq;
            dB[0]  = f2bf(b0 * facB);
            dB[32] = f2bf(b1 * facB);
        }
    }
}

// ---------------- output projection (fp32 out + bias) ---------------------
// Grid 512 (2 blocks/CU), XCD-grouped: b = id&7. 128M x 64N tiles.
__global__ __launch_bounds__(256) void proj_out_kernel(
        const unsigned short* __restrict__ AT, const unsigned short* __restrict__ Wo,
        const float* __restrict__ bo, float* __restrict__ out) {
    const int id = blockIdx.x;
    const int b = id & 7, inner = id >> 3;
    const int o0 = (inner & 3) * 128, n0 = (inner >> 2) * 64;
    f32x4 acc[4][2];
#pragma unroll
    for (int i = 0; i < 4; i++)
#pragma unroll
        for (int j = 0; j < 2; j++)
#pragma unroll
            for (int r = 0; r < 4; r++) acc[i][j][r] = 0.f;

    gemm128x64(Wo + (size_t)o0 * CH, AT + ((size_t)b * NPIX + n0) * CH, acc);

    const int lane = threadIdx.x & 63;
    const int wm = (threadIdx.x >> 6) & 1, wn = threadIdx.x >> 7;
#pragma unroll
    for (int i = 0; i < 4; i++) {
        const int ob = o0 + wm * 64 + i * 16 + (lane >> 4) * 4;
        float b4[4];
#pragma unroll
        for (int r = 0; r < 4; r++) b4[r] = bo[ob + r];
#pragma unroll
        for (int j = 0; j < 2; j++) {
            const int n = n0 + wn * 32 + j * 16 + (lane & 15);
#pragma unroll
            for (int r = 0; r < 4; r++)
                out[((size_t)b * CH + ob + r) * NPIX + n] = acc[i][j][r] + b4[r];
        }
    }
}

extern "C" void kernel_launch(void* const* d_in, const int* in_sizes, int n_in,
                              void* d_out, int out_size, void* d_ws, size_t ws_size,
                              hipStream_t stream) {
    const float* x   = (const float*)d_in[0];
    const float* ctx = (const float*)d_in[1];
    const float* Wq  = (const float*)d_in[2];
    const float* bq  = (const float*)d_in[3];
    const float* Wk  = (const float*)d_in[4];
    const float* bk  = (const float*)d_in[5];
    const float* Wv  = (const float*)d_in[6];
    const float* bv  = (const float*)d_in[7];
    const float* Wo  = (const float*)d_in[8];
    const float* bo  = (const float*)d_in[9];
    float* out = (float*)d_out;

    char* ws = (char*)d_ws;
    unsigned short* XT  = (unsigned short*)(ws);                 //  8 MB [b][n][c] bf16
    unsigned short* CT  = (unsigned short*)(ws + 8388608);       //  8 MB
    unsigned short* Wbf = (unsigned short*)(ws + 16777216);      //  2 MB Wq|Wk|Wv|Wo
    unsigned short* Q   = (unsigned short*)(ws + 18874368);      //  8 MB [b][h][n][d]
    unsigned short* K   = (unsigned short*)(ws + 27262976);      //  8 MB [b][h][n][d]
    unsigned short* V   = (unsigned short*)(ws + 35651584);      //  8 MB [bh][kb][d&31][d>>5][k32]
    unsigned short* AT  = XT;   // XT dead after proj_qkv; alias for attention output

    prep_kernel<<<9216, 256, 0, stream>>>(Wq, Wk, Wv, Wo, Wbf, x, ctx, XT, CT);
    proj_qkv_kernel<<<768, 256, 0, stream>>>(XT, CT, Wbf, bq, bk, bv, Q, K, V);
    attn_kernel<<<1024, 128, 0, stream>>>(Q, K, V, AT);
    proj_out_kernel<<<512, 256, 0, stream>>>(AT, Wbf + 3 * 262144, bo, out);
}

// Round 18
// 79.067 us; speedup vs baseline: 1.0548x; 1.0097x over previous
//
#include <hip/hip_runtime.h>
#include <stdint.h>

#define NB   8
#define CH   512
#define NPIX 1024
#define DH   64

typedef float  f32x4  __attribute__((ext_vector_type(4)));
typedef float  f32x16 __attribute__((ext_vector_type(16)));
typedef __bf16 bf16x8 __attribute__((ext_vector_type(8)));
typedef unsigned int u32x4 __attribute__((ext_vector_type(4)));

static __device__ __forceinline__ unsigned short f2bf(float f) {
    unsigned int u = __builtin_bit_cast(unsigned int, f);
    u += 0x7FFFu + ((u >> 16) & 1u);   // RNE
    return (unsigned short)(u >> 16);
}

static __device__ __forceinline__ bf16x8 ld_bf8(const unsigned short* p) {
    return *reinterpret_cast<const bf16x8*>(p);
}

static __device__ __forceinline__ unsigned int cvtpk_bf16(float lo, float hi) {
    unsigned int r;
    asm("v_cvt_pk_bf16_f32 %0,%1,%2" : "=v"(r) : "v"(lo), "v"(hi));
    return r;
}

// raw v_exp_f32 (2^x); |S| < 40 so no range fixup needed.
static __device__ __forceinline__ float fexp2(float x) {
    float r;
    asm("v_exp_f32 %0, %1" : "=v"(r) : "v"(x));
    return r;
}

// v_permlane32_swap_b32 a, b:  a' = [a.lo32 | b.lo32], b' = [a.hi32 | b.hi32]
static __device__ __forceinline__ void plswap(unsigned int& a, unsigned int& b) {
    asm("v_permlane32_swap_b32 %0, %1" : "+v"(a), "+v"(b));
}

// async global->LDS, 16B per lane; LDS dest = wave-uniform base + lane*16
static __device__ __forceinline__ void glds16(const unsigned short* g, void* l) {
    __builtin_amdgcn_global_load_lds(
        (const __attribute__((address_space(1))) unsigned int*)g,
        (__attribute__((address_space(3))) unsigned int*)l,
        16, 0, 0);
}

#define WAIT_VMCNT_8() asm volatile("s_waitcnt vmcnt(8)" ::: "memory")
#define WAIT_VMCNT_4() asm volatile("s_waitcnt vmcnt(4)" ::: "memory")
#define WAIT_VMCNT_3() asm volatile("s_waitcnt vmcnt(3)" ::: "memory")
#define WAIT_VMCNT_0() asm volatile("s_waitcnt vmcnt(0)" ::: "memory")
#define WAIT_LGKM_0()  asm volatile("s_waitcnt lgkmcnt(0)" ::: "memory")

// ---------------- fused prep: weights->bf16 + input transpose -------------
__global__ __launch_bounds__(256) void prep_kernel(
        const float* __restrict__ Wq, const float* __restrict__ Wk,
        const float* __restrict__ Wv, const float* __restrict__ Wo,
        unsigned short* __restrict__ Wbf,
        const float* __restrict__ x, const float* __restrict__ ctx,
        unsigned short* __restrict__ XT, unsigned short* __restrict__ CT) {
    __shared__ float tile[32][33];
    const int bid = blockIdx.x;
    if (bid < 1024) {
        int idx4 = (bid * 256 + threadIdx.x) * 4;      // 0..2^20-1 step 4
        int which = idx4 >> 18;
        int off   = idx4 & 0x3FFFF;
        const float* src = which == 0 ? Wq : which == 1 ? Wk : which == 2 ? Wv : Wo;
        float4 v = *(const float4*)(src + off);
        unsigned int lo = ((unsigned)f2bf(v.y) << 16) | f2bf(v.x);
        unsigned int hi = ((unsigned)f2bf(v.w) << 16) | f2bf(v.z);
        *(uint2*)(Wbf + idx4) = make_uint2(lo, hi);
        return;
    }
    const int t0 = bid - 1024;                 // 0..8191
    const int z  = t0 >> 9;                    // 0..15 : tensor(2) x batch(8)
    const int cx = t0 & 15, ny = (t0 >> 4) & 31;
    const float* src = (z < 8) ? x : ctx;
    unsigned short* dst = (z < 8) ? XT : CT;
    const int b  = z & 7;
    const int c0 = cx * 32, n0 = ny * 32;
    const int t  = threadIdx.x;
    const int r  = t >> 3, ch4 = (t & 7) * 4;
    const float* s = src + (size_t)b * CH * NPIX + (size_t)(c0 + r) * NPIX + n0 + ch4;
    float4 v4 = *(const float4*)s;
    tile[r][ch4] = v4.x; tile[r][ch4 + 1] = v4.y;
    tile[r][ch4 + 2] = v4.z; tile[r][ch4 + 3] = v4.w;
    __syncthreads();
    unsigned int lo = ((unsigned)f2bf(tile[ch4 + 1][r]) << 16) | f2bf(tile[ch4][r]);
    unsigned int hw = ((unsigned)f2bf(tile[ch4 + 3][r]) << 16) | f2bf(tile[ch4 + 2][r]);
    *(uint2*)(dst + (size_t)b * NPIX * CH + (size_t)(n0 + r) * CH + c0 + ch4)
        = make_uint2(lo, hw);
}

// ---------------- 128x128xK512 GEMM core (BK=32) --------------------------
// 3-buffer rotation, ONE barrier per K-step, staging at iteration top.
static __device__ __forceinline__ void gemm128(
        const unsigned short* __restrict__ Wp,
        const unsigned short* __restrict__ Xp,
        f32x4 acc[4][4]) {
    __shared__ __align__(16) unsigned short lA[3][128][32];
    __shared__ __align__(16) unsigned short lB[3][128][32];
    const int tid  = threadIdx.x;
    const int lane = tid & 63;
    const int wv   = tid >> 6;
    const int wm   = wv & 1, wn = tid >> 7;

    const unsigned short* gA = Wp + (size_t)(wv * 32 + (lane >> 2)) * CH + (lane & 3) * 8;
    const unsigned short* gB = Xp + (size_t)(wv * 32 + (lane >> 2)) * CH + (lane & 3) * 8;

    auto stage = [&](int kt, int buf) {
        const int k0 = kt * 32;
        char* dA = (char*)&lA[buf][0][0] + wv * 2048;
        char* dB = (char*)&lB[buf][0][0] + wv * 2048;
        glds16(gA + k0,           dA);
        glds16(gA + k0 + 16 * CH, dA + 1024);
        glds16(gB + k0,           dB);
        glds16(gB + k0 + 16 * CH, dB + 1024);
    };

    stage(0, 0);
    stage(1, 1);

#pragma unroll 1
    for (int kt = 0; kt < 16; kt++) {
        if (kt < 15) { WAIT_VMCNT_4(); } else { WAIT_VMCNT_0(); }
        __builtin_amdgcn_s_barrier();
        if (kt + 2 < 16) stage(kt + 2, (kt + 2) % 3);
        const int buf = kt % 3;
        bf16x8 af[4], bfrag[4];
#pragma unroll
        for (int i = 0; i < 4; i++)
            af[i] = ld_bf8(&lA[buf][wm * 64 + i * 16 + (lane & 15)][(lane >> 4) * 8]);
#pragma unroll
        for (int j = 0; j < 4; j++)
            bfrag[j] = ld_bf8(&lB[buf][wn * 64 + j * 16 + (lane & 15)][(lane >> 4) * 8]);
#pragma unroll
        for (int i = 0; i < 4; i++)
#pragma unroll
            for (int j = 0; j < 4; j++)
                acc[i][j] = __builtin_amdgcn_mfma_f32_16x16x32_bf16(af[i], bfrag[j], acc[i][j], 0, 0, 0);
    }
}

// ---------------- 128M x 64N x K512 GEMM core (BK=32) ---------------------
// N-split variant: used ONLY by proj_out (grid-starved at 128x128).
static __device__ __forceinline__ void gemm128x64(
        const unsigned short* __restrict__ Wp,
        const unsigned short* __restrict__ Xp,
        f32x4 acc[4][2]) {
    __shared__ __align__(16) unsigned short lA[3][128][32];
    __shared__ __align__(16) unsigned short lB[3][64][32];
    const int tid  = threadIdx.x;
    const int lane = tid & 63;
    const int wv   = tid >> 6;
    const int wm   = wv & 1, wn = wv >> 1;

    const unsigned short* gA = Wp + (size_t)(wv * 32 + (lane >> 2)) * CH + (lane & 3) * 8;
    const unsigned short* gB = Xp + (size_t)(wv * 16 + (lane >> 2)) * CH + (lane & 3) * 8;

    auto stage = [&](int kt, int buf) {
        const int k0 = kt * 32;
        char* dA = (char*)&lA[buf][0][0] + wv * 2048;
        char* dB = (char*)&lB[buf][0][0] + wv * 1024;
        glds16(gA + k0,           dA);
        glds16(gA + k0 + 16 * CH, dA + 1024);
        glds16(gB + k0,           dB);
    };

    stage(0, 0);
    stage(1, 1);

#pragma unroll 1
    for (int kt = 0; kt < 16; kt++) {
        if (kt < 15) { WAIT_VMCNT_3(); } else { WAIT_VMCNT_0(); }
        __builtin_amdgcn_s_barrier();
        if (kt + 2 < 16) stage(kt + 2, (kt + 2) % 3);
        const int buf = kt % 3;
        bf16x8 af[4], bfrag[2];
#pragma unroll
        for (int i = 0; i < 4; i++)
            af[i] = ld_bf8(&lA[buf][wm * 64 + i * 16 + (lane & 15)][(lane >> 4) * 8]);
#pragma unroll
        for (int j = 0; j < 2; j++)
            bfrag[j] = ld_bf8(&lB[buf][wn * 32 + j * 16 + (lane & 15)][(lane >> 4) * 8]);
#pragma unroll
        for (int i = 0; i < 4; i++)
#pragma unroll
            for (int j = 0; j < 2; j++)
                acc[i][j] = __builtin_amdgcn_mfma_f32_16x16x32_bf16(af[i], bfrag[j], acc[i][j], 0, 0, 0);
    }
}

// ---------------- fused Q/K/V projection (128x128, grid 768) --------------
// 1D grid, XCD-grouped: b = id&7. V stored as [bh][kb=n/32][d&31][d>>5][n%32].
__global__ __launch_bounds__(256) void proj_qkv_kernel(
        const unsigned short* __restrict__ XT, const unsigned short* __restrict__ CT,
        const unsigned short* __restrict__ Wbf,
        const float* __restrict__ bq, const float* __restrict__ bk, const float* __restrict__ bv,
        unsigned short* __restrict__ Q, unsigned short* __restrict__ K, unsigned short* __restrict__ V) {
    const int id = blockIdx.x;
    const int b = id & 7, mode = id >> 8, inner = (id >> 3) & 31;
    const int o0 = (inner & 3) * 128, n0 = (inner >> 2) * 128;
    const unsigned short* W = Wbf + (size_t)mode * CH * CH;
    const unsigned short* X = (mode == 0 ? XT : CT) + (size_t)b * NPIX * CH;
    const float* bias = mode == 0 ? bq : mode == 1 ? bk : bv;

    f32x4 acc[4][4];
#pragma unroll
    for (int i = 0; i < 4; i++)
#pragma unroll
        for (int j = 0; j < 4; j++)
#pragma unroll
            for (int r = 0; r < 4; r++) acc[i][j][r] = 0.f;

    gemm128(W + (size_t)o0 * CH, X + (size_t)n0 * CH, acc);

    const int lane = threadIdx.x & 63;
    const int wm = (threadIdx.x >> 6) & 1, wn = threadIdx.x >> 7;
    const float qs = 0.125f * 1.44269504088896340736f;   // dim_head^-0.5 * log2(e)
#pragma unroll
    for (int i = 0; i < 4; i++) {
        const int ob = o0 + wm * 64 + i * 16 + (lane >> 4) * 4;
        const int h = ob >> 6, dd = ob & 63;
        float b4[4];
#pragma unroll
        for (int r = 0; r < 4; r++) b4[r] = bias[ob + r];
#pragma unroll
        for (int j = 0; j < 4; j++) {
            const int n = n0 + wn * 64 + j * 16 + (lane & 15);
            float v[4];
#pragma unroll
            for (int r = 0; r < 4; r++) v[r] = acc[i][j][r] + b4[r];
            if (mode == 0) {
#pragma unroll
                for (int r = 0; r < 4; r++) v[r] *= qs;
            }
            if (mode <= 1) {
                unsigned int lo = (unsigned)f2bf(v[0]) | ((unsigned)f2bf(v[1]) << 16);
                unsigned int hi = (unsigned)f2bf(v[2]) | ((unsigned)f2bf(v[3]) << 16);
                unsigned short* dst = (mode == 0 ? Q : K) +
                    (((size_t)(b * 8 + h) * NPIX) + n) * DH + dd;
                *(uint2*)dst = make_uint2(lo, hi);
            } else {
#pragma unroll
                for (int r = 0; r < 4; r++) {
                    int d = dd + r;
                    V[(((size_t)(b * 8 + h) * 32 + (n >> 5)) * 2048)
                      + (size_t)(d & 31) * 64 + (d >> 5) * 32 + (n & 31)] = f2bf(v[r]);
                }
            }
        }
    }
}

// ---------------- flash attention v14 (proven: R14/R16) -------------------
// 2 waves/block, wave-private K/V LDS streams, cross-iteration QK pipeline,
// max-free softmax, permlane pack, pure-add 2-way merge.
__global__ __launch_bounds__(128) void attn_kernel(
        const unsigned short* __restrict__ Qg, const unsigned short* __restrict__ Kg,
        const unsigned short* __restrict__ Vg, unsigned short* __restrict__ AT) {
    __shared__ __align__(16) unsigned short ldsS[2][2][2][2048]; // [wave][buf][K/V][2048]
    __shared__ float lbuf[64];

    const int p  = blockIdx.x;
    const int local = p >> 3;
    const int bh = ((p & 7) << 3) | (local >> 4);
    const int qb = local & 15;
    const int q0 = qb * 64;
    const int tid = threadIdx.x, wave = tid >> 6, lane = tid & 63;
    const int lq = lane & 31, hi = lane >> 5, lql7 = lq & 7;
    const int key0 = wave * 512;

    const unsigned short* Qp = Qg + ((size_t)bh * NPIX + q0 + lq) * DH + hi * 8;
    bf16x8 qa[4], qbf[4];
#pragma unroll
    for (int ds = 0; ds < 4; ds++) {
        qa[ds]  = ld_bf8(Qp + ds * 16);
        qbf[ds] = ld_bf8(Qp + 32 * DH + ds * 16);
    }

    f32x16 oA0, oA1, oB0, oB1, zro;
#pragma unroll
    for (int r = 0; r < 16; r++) {
        oA0[r] = 0.f; oA1[r] = 0.f; oB0[r] = 0.f; oB1[r] = 0.f; zro[r] = 0.f;
    }
    float lA = 0.f, lB = 0.f;

    const int swz = (((lane & 7) ^ ((lane >> 3) & 7)) << 3);
    const unsigned short* gK = Kg + ((size_t)bh * NPIX + key0 + (lane >> 3)) * DH + swz;
    const unsigned short* gV = Vg + (size_t)bh * 65536 + (size_t)(key0 >> 5) * 2048
                                  + (lane >> 3) * 64 + swz;

    auto stage = [&](int t, int buf) {
        const unsigned short* sk = gK + (size_t)t * 32 * DH;
        char* dK = (char*)&ldsS[wave][buf][0][0];
        glds16(sk,           dK);
        glds16(sk +  8 * DH, dK + 1024);
        glds16(sk + 16 * DH, dK + 2048);
        glds16(sk + 24 * DH, dK + 3072);
        const unsigned short* sv = gV + (size_t)t * 2048;
        char* dV = (char*)&ldsS[wave][buf][1][0];
        glds16(sv,        dV);
        glds16(sv +  512, dV + 1024);
        glds16(sv + 1024, dV + 2048);
        glds16(sv + 1536, dV + 3072);
    };

    stage(0, 0);
    stage(1, 1);

    // ---- prologue: QK(0) (tile 0 staged once vmcnt <= 8)
    f32x16 sA, sB;
    {
        WAIT_VMCNT_8();
        const unsigned short* kb = &ldsS[wave][0][0][0] + lq * 64;
        bf16x8 kf0 = ld_bf8(kb + (((0 + hi) ^ lql7) << 3));
        bf16x8 kf1 = ld_bf8(kb + (((2 + hi) ^ lql7) << 3));
        bf16x8 kf2 = ld_bf8(kb + (((4 + hi) ^ lql7) << 3));
        bf16x8 kf3 = ld_bf8(kb + (((6 + hi) ^ lql7) << 3));
        __builtin_amdgcn_s_setprio(1);
        sA = __builtin_amdgcn_mfma_f32_32x32x16_bf16(kf0, qa[0],  zro, 0, 0, 0);
        sA = __builtin_amdgcn_mfma_f32_32x32x16_bf16(kf1, qa[1],  sA, 0, 0, 0);
        sA = __builtin_amdgcn_mfma_f32_32x32x16_bf16(kf2, qa[2],  sA, 0, 0, 0);
        sA = __builtin_amdgcn_mfma_f32_32x32x16_bf16(kf3, qa[3],  sA, 0, 0, 0);
        sB = __builtin_amdgcn_mfma_f32_32x32x16_bf16(kf0, qbf[0], zro, 0, 0, 0);
        sB = __builtin_amdgcn_mfma_f32_32x32x16_bf16(kf1, qbf[1], sB, 0, 0, 0);
        sB = __builtin_amdgcn_mfma_f32_32x32x16_bf16(kf2, qbf[2], sB, 0, 0, 0);
        sB = __builtin_amdgcn_mfma_f32_32x32x16_bf16(kf3, qbf[3], sB, 0, 0, 0);
        __builtin_amdgcn_s_setprio(0);
    }

#pragma unroll 1
    for (int t = 0; t < 16; ++t) {
        const int cur = t & 1;
        // ---- V(t) ds_reads issued first: latency drains under softmax
        const unsigned short* vb = &ldsS[wave][cur][1][0] + lq * 64;
        bf16x8 v00 = ld_bf8(vb + (((0 + hi) ^ lql7) << 3));   // d=lq,    keys 0-15
        bf16x8 v01 = ld_bf8(vb + (((2 + hi) ^ lql7) << 3));   // d=lq,    keys 16-31
        bf16x8 v10 = ld_bf8(vb + (((4 + hi) ^ lql7) << 3));   // d=32+lq, keys 0-15
        bf16x8 v11 = ld_bf8(vb + (((6 + hi) ^ lql7) << 3));   // d=32+lq, keys 16-31

        // ---- softmax(t) on sA/sB (VALU; consumes scores into pa regs)
#pragma unroll
        for (int r = 0; r < 16; r++) { sA[r] = fexp2(sA[r]); sB[r] = fexp2(sB[r]); }
        {
            float a8[8], b8[8], a4[4], b4[4];
#pragma unroll
            for (int i = 0; i < 8; i++) { a8[i] = sA[2*i] + sA[2*i+1]; b8[i] = sB[2*i] + sB[2*i+1]; }
#pragma unroll
            for (int i = 0; i < 4; i++) { a4[i] = a8[2*i] + a8[2*i+1]; b4[i] = b8[2*i] + b8[2*i+1]; }
            lA += (a4[0] + a4[1]) + (a4[2] + a4[3]);
            lB += (b4[0] + b4[1]) + (b4[2] + b4[3]);
        }
        bf16x8 paA[2], paB[2];
#pragma unroll
        for (int ks = 0; ks < 2; ks++) {
            const int bse = ks * 8;
            unsigned int X0 = cvtpk_bf16(sA[bse + 0], sA[bse + 1]);
            unsigned int X1 = cvtpk_bf16(sA[bse + 2], sA[bse + 3]);
            unsigned int X2 = cvtpk_bf16(sA[bse + 4], sA[bse + 5]);
            unsigned int X3 = cvtpk_bf16(sA[bse + 6], sA[bse + 7]);
            plswap(X0, X2); plswap(X1, X3);
            u32x4 wa; wa[0] = X0; wa[1] = X1; wa[2] = X2; wa[3] = X3;
            paA[ks] = __builtin_bit_cast(bf16x8, wa);
            unsigned int Y0 = cvtpk_bf16(sB[bse + 0], sB[bse + 1]);
            unsigned int Y1 = cvtpk_bf16(sB[bse + 2], sB[bse + 3]);
            unsigned int Y2 = cvtpk_bf16(sB[bse + 4], sB[bse + 5]);
            unsigned int Y3 = cvtpk_bf16(sB[bse + 6], sB[bse + 7]);
            plswap(Y0, Y2); plswap(Y1, Y3);
            u32x4 wb; wb[0] = Y0; wb[1] = Y1; wb[2] = Y2; wb[3] = Y3;
            paB[ks] = __builtin_bit_cast(bf16x8, wb);
        }

        // ---- V in regs; safe to overwrite buf[cur] (K(t) reads retired)
        WAIT_LGKM_0();
        __builtin_amdgcn_sched_barrier(0);
        if (t + 2 < 16) stage(t + 2, cur);
        __builtin_amdgcn_sched_barrier(0);

        // ---- QK(t+1): counted wait (t<14: t+2 outstanding -> vmcnt(8)
        // proves t+1 done; t==14: no stage(16), must drain to 0)
        if (t < 15) {
            if (t < 14) { WAIT_VMCNT_8(); } else { WAIT_VMCNT_0(); }
            const unsigned short* kb = &ldsS[wave][cur ^ 1][0][0] + lq * 64;
            bf16x8 kf0 = ld_bf8(kb + (((0 + hi) ^ lql7) << 3));
            bf16x8 kf1 = ld_bf8(kb + (((2 + hi) ^ lql7) << 3));
            bf16x8 kf2 = ld_bf8(kb + (((4 + hi) ^ lql7) << 3));
            bf16x8 kf3 = ld_bf8(kb + (((6 + hi) ^ lql7) << 3));
            __builtin_amdgcn_s_setprio(1);
            sA = __builtin_amdgcn_mfma_f32_32x32x16_bf16(kf0, qa[0],  zro, 0, 0, 0);
            sA = __builtin_amdgcn_mfma_f32_32x32x16_bf16(kf1, qa[1],  sA, 0, 0, 0);
            sA = __builtin_amdgcn_mfma_f32_32x32x16_bf16(kf2, qa[2],  sA, 0, 0, 0);
            sA = __builtin_amdgcn_mfma_f32_32x32x16_bf16(kf3, qa[3],  sA, 0, 0, 0);
            sB = __builtin_amdgcn_mfma_f32_32x32x16_bf16(kf0, qbf[0], zro, 0, 0, 0);
            sB = __builtin_amdgcn_mfma_f32_32x32x16_bf16(kf1, qbf[1], sB, 0, 0, 0);
            sB = __builtin_amdgcn_mfma_f32_32x32x16_bf16(kf2, qbf[2], sB, 0, 0, 0);
            sB = __builtin_amdgcn_mfma_f32_32x32x16_bf16(kf3, qbf[3], sB, 0, 0, 0);
            __builtin_amdgcn_s_setprio(0);
        }

        // ---- PV(t): issue window covers QK(t+1)'s drain
        __builtin_amdgcn_s_setprio(1);
        oA0 = __builtin_amdgcn_mfma_f32_32x32x16_bf16(paA[0], v00, oA0, 0, 0, 0);
        oB0 = __builtin_amdgcn_mfma_f32_32x32x16_bf16(paB[0], v00, oB0, 0, 0, 0);
        oA1 = __builtin_amdgcn_mfma_f32_32x32x16_bf16(paA[0], v10, oA1, 0, 0, 0);
        oB1 = __builtin_amdgcn_mfma_f32_32x32x16_bf16(paB[0], v10, oB1, 0, 0, 0);
        oA0 = __builtin_amdgcn_mfma_f32_32x32x16_bf16(paA[1], v01, oA0, 0, 0, 0);
        oB0 = __builtin_amdgcn_mfma_f32_32x32x16_bf16(paB[1], v01, oB0, 0, 0, 0);
        oA1 = __builtin_amdgcn_mfma_f32_32x32x16_bf16(paA[1], v11, oA1, 0, 0, 0);
        oB1 = __builtin_amdgcn_mfma_f32_32x32x16_bf16(paB[1], v11, oB1, 0, 0, 0);
        __builtin_amdgcn_s_setprio(0);
    }

    // ---- merge (pure add): wave1 posts into its dead staging LDS; one
    // barrier; wave0 adds + writes.
    lA += __shfl_xor(lA, 32);
    lB += __shfl_xor(lB, 32);
    float* obuf = (float*)&ldsS[1][0][0][0];
    if (wave == 1) {
#pragma unroll
        for (int r = 0; r < 16; r++) {
            obuf[(0 * 16 + r) * 64 + lane] = oA0[r];
            obuf[(1 * 16 + r) * 64 + lane] = oA1[r];
            obuf[(2 * 16 + r) * 64 + lane] = oB0[r];
            obuf[(3 * 16 + r) * 64 + lane] = oB1[r];
        }
        if (lane < 32) { lbuf[lq] = lA; lbuf[32 + lq] = lB; }
    }
    __syncthreads();
    if (wave == 0) {
        float invA = 1.0f / (lA + lbuf[lq]);
        float invB = 1.0f / (lB + lbuf[32 + lq]);
        const int b = bh >> 3, h = bh & 7;
#pragma unroll
        for (int r = 0; r < 16; r++) {
            float a0 = oA0[r] + obuf[(0 * 16 + r) * 64 + lane];
            float a1 = oA1[r] + obuf[(1 * 16 + r) * 64 + lane];
            float b0 = oB0[r] + obuf[(2 * 16 + r) * 64 + lane];
            float b1 = oB1[r] + obuf[(3 * 16 + r) * 64 + lane];
            int crow = (r & 3) + 8 * (r >> 2) + 4 * hi;
            float facA = __shfl(invA, crow);
            float facB = __shfl(invB, crow);
            unsigned short* dA = AT + ((size_t)b * NPIX + q0 + crow) * CH + h * 64 + lq;
            dA[0]  = f2bf(a0 * facA);
            dA[32] = f2bf(a1 * facA);
            unsigned short* dB = AT + ((size_t)b * NPIX + q0 + 32 + crow) * CH + h * 64 + lq;
            dB[0]  = f2bf(b0 * facB);
            dB[32] = f2bf(b1 * facB);
        }
    }
}

// ---------------- output projection (fp32 out + bias) ---------------------
// Grid 512 (2 blocks/CU), XCD-grouped: b = id&7. 128M x 64N tiles.
__global__ __launch_bounds__(256) void proj_out_kernel(
        const unsigned short* __restrict__ AT, const unsigned short* __restrict__ Wo,
        const float* __restrict__ bo, float* __restrict__ out) {
    const int id = blockIdx.x;
    const int b = id & 7, inner = id >> 3;
    const int o0 = (inner & 3) * 128, n0 = (inner >> 2) * 64;
    f32x4 acc[4][2];
#pragma unroll
    for (int i = 0; i < 4; i++)
#pragma unroll
        for (int j = 0; j < 2; j++)
#pragma unroll
            for (int r = 0; r < 4; r++) acc[i][j][r] = 0.f;

    gemm128x64(Wo + (size_t)o0 * CH, AT + ((size_t)b * NPIX + n0) * CH, acc);

    const int lane = threadIdx.x & 63;
    const int wm = (threadIdx.x >> 6) & 1, wn = threadIdx.x >> 7;
#pragma unroll
    for (int i = 0; i < 4; i++) {
        const int ob = o0 + wm * 64 + i * 16 + (lane >> 4) * 4;
        float b4[4];
#pragma unroll
        for (int r = 0; r < 4; r++) b4[r] = bo[ob + r];
#pragma unroll
        for (int j = 0; j < 2; j++) {
            const int n = n0 + wn * 32 + j * 16 + (lane & 15);
#pragma unroll
            for (int r = 0; r < 4; r++)
                out[((size_t)b * CH + ob + r) * NPIX + n] = acc[i][j][r] + b4[r];
        }
    }
}

extern "C" void kernel_launch(void* const* d_in, const int* in_sizes, int n_in,
                              void* d_out, int out_size, void* d_ws, size_t ws_size,
                              hipStream_t stream) {
    const float* x   = (const float*)d_in[0];
    const float* ctx = (const float*)d_in[1];
    const float* Wq  = (const float*)d_in[2];
    const float* bq  = (const float*)d_in[3];
    const float* Wk  = (const float*)d_in[4];
    const float* bk  = (const float*)d_in[5];
    const float* Wv  = (const float*)d_in[6];
    const float* bv  = (const float*)d_in[7];
    const float* Wo  = (const float*)d_in[8];
    const float* bo  = (const float*)d_in[9];
    float* out = (float*)d_out;

    char* ws = (char*)d_ws;
    unsigned short* XT  = (unsigned short*)(ws);                 //  8 MB [b][n][c] bf16
    unsigned short* CT  = (unsigned short*)(ws + 8388608);       //  8 MB
    unsigned short* Wbf = (unsigned short*)(ws + 16777216);      //  2 MB Wq|Wk|Wv|Wo
    unsigned short* Q   = (unsigned short*)(ws + 18874368);      //  8 MB [b][h][n][d]
    unsigned short* K   = (unsigned short*)(ws + 27262976);      //  8 MB [b][h][n][d]
    unsigned short* V   = (unsigned short*)(ws + 35651584);      //  8 MB [bh][kb][d&31][d>>5][k32]
    unsigned short* AT  = XT;   // XT dead after proj_qkv; alias for attention output

    prep_kernel<<<9216, 256, 0, stream>>>(Wq, Wk, Wv, Wo, Wbf, x, ctx, XT, CT);
    proj_qkv_kernel<<<768, 256, 0, stream>>>(XT, CT, Wbf, bq, bk, bv, Q, K, V);
    attn_kernel<<<1024, 128, 0, stream>>>(Q, K, V, AT);
    proj_out_kernel<<<512, 256, 0, stream>>>(AT, Wbf + 3 * 262144, bo, out);
}